// Round 7
// baseline (157.966 us; speedup 1.0000x reference)
//
#include <hip/hip_runtime.h>

#define B_ 2
#define L_ 256
#define D_ 512
#define H_ 8
#define DV_ 64
#define NEGINF 1e12f

// ws layout (float offsets):
#define WS_VALUE 0          // [B*H][L][DV]      = 262144
#define WS_WR    262144     // f32 [512][8]      = 4096
#define WS_WRFRG 266240     // bf16 frags 16KB   = 4096 floats (8192 ushorts)
#define WS_SSRC  270336     // [B*H][L]          = 4096
#define WS_STGT  274432     // [B*H][L]          = 4096
#define WS_SREL  278528     // [bi][h][j]        = 512*2048 = 1048576

typedef __attribute__((ext_vector_type(8))) short bf16x8;
typedef __attribute__((ext_vector_type(4))) float f32x4;

__device__ inline unsigned short f2bf(float f) {
    unsigned u = __float_as_uint(f);
    unsigned r = ((u >> 16) & 1) + 0x7FFFu;
    return (unsigned short)((u + r) >> 16);
}

// ---------------- Kernel A: WR[k][h] = sum_d W_relation[k][h*64+d] * w_rel[h][d]
__global__ __launch_bounds__(256) void k_wr(const float* __restrict__ Wrel,
                                            const float* __restrict__ wrel,
                                            float* __restrict__ WR) {
    int flat = blockIdx.x * 256 + threadIdx.x;   // 4096 = 512*8
    int k = flat >> 3, h = flat & 7;
    const float* a = Wrel + k * 512 + h * 64;
    const float* b = wrel + h * 64;
    float s = 0.f;
#pragma unroll
    for (int d = 0; d < 64; d += 4) {
        float4 x = *(const float4*)(a + d);
        float4 y = *(const float4*)(b + d);
        s += x.x * y.x + x.y * y.y + x.z * y.z + x.w * y.w;
    }
    WR[k * 8 + h] = s;
}

// ---------------- Kernel A2: pack WR into mfma B-frag layout (bf16).
// Frag slot t = kt*64 + lane (kt=0..15, K=32 each): lane holds
// B[k = kt*32 + (lane>>4)*8 + e][n = lane&15] (n>=8 -> 0), e=0..7.
__global__ __launch_bounds__(256) void k_frag(const float* __restrict__ WR,
                                              unsigned short* __restrict__ WRfrag) {
    int t = blockIdx.x * 256 + threadIdx.x;      // 0..1023
    int kt = t >> 6, lane = t & 63;
    int sg = lane >> 4, n = lane & 15;
    unsigned int w[4];
#pragma unroll
    for (int p = 0; p < 4; ++p) {
        int k0 = kt * 32 + sg * 8 + 2 * p;
        float v0 = (n < 8) ? WR[k0 * 8 + n] : 0.f;
        float v1 = (n < 8) ? WR[(k0 + 1) * 8 + n] : 0.f;
        w[p] = (unsigned)f2bf(v0) | ((unsigned)f2bf(v1) << 16);
    }
    *(uint4*)&WRfrag[(size_t)t * 8] = make_uint4(w[0], w[1], w[2], w[3]);
}

// ---------------- Kernel B: value = inp @ W_value, + fused s_src/s_tgt epilogue
__global__ __launch_bounds__(256) void k_value(const float* __restrict__ inp,
                                               const float* __restrict__ Wv,
                                               const float* __restrict__ wsrc,
                                               const float* __restrict__ wtgt,
                                               float* __restrict__ value,
                                               float* __restrict__ s_src,
                                               float* __restrict__ s_tgt) {
    int blk = blockIdx.x;          // 256 blocks = 128 row-tiles x 2 col-halves
    int ct  = blk & 1;
    int rt  = blk >> 1;
    int n   = ct * 256 + threadIdx.x;   // output col 0..511
    int r0  = rt * 4;
    const float* i0 = inp + (size_t)(r0 + 0) * 512;
    const float* i1 = inp + (size_t)(r0 + 1) * 512;
    const float* i2 = inp + (size_t)(r0 + 2) * 512;
    const float* i3 = inp + (size_t)(r0 + 3) * 512;
    float a0 = 0.f, a1 = 0.f, a2 = 0.f, a3 = 0.f;
#pragma unroll 16
    for (int k = 0; k < 512; ++k) {
        float w = Wv[(size_t)k * 512 + n];
        a0 = fmaf(i0[k], w, a0);
        a1 = fmaf(i1[k], w, a1);
        a2 = fmaf(i2[k], w, a2);
        a3 = fmaf(i3[k], w, a3);
    }
    int h = n >> 6, dv = n & 63;
    float acc[4] = {a0, a1, a2, a3};
    float wsv = wsrc[h * 64 + dv];
    float wtv = wtgt[h * 64 + dv];
#pragma unroll
    for (int r = 0; r < 4; ++r) {
        int row = r0 + r;
        int b = row >> 8, l = row & 255;
        value[(((size_t)(b * 8 + h)) * 256 + l) * 64 + dv] = acc[r];
        float ss = acc[r] * wsv;
        float st = acc[r] * wtv;
#pragma unroll
        for (int off = 32; off >= 1; off >>= 1) {
            ss += __shfl_xor(ss, off);
            st += __shfl_xor(st, off);
        }
        if (dv == 0) {
            s_src[(size_t)(b * 8 + h) * 256 + l] = ss;
            s_tgt[(size_t)(b * 8 + h) * 256 + l] = st;
        }
    }
}

// ---------------- Kernel C: srel via MFMA. Block = 64 rows (4 waves x 16).
// A-frag direct from global: lane reads rel[row0 + (lane&15)][kt*32 + (lane>>4)*8 + 0..7]
// (two float4s; per instr the 4 k-slot lanes of a row form one 64B line -> 16 lines/instr).
// No LDS, no barriers, no shuffles. Reduction on the matrix pipe.
__global__ __launch_bounds__(256, 3) void k_srel(const float* __restrict__ rel,
                                                 const unsigned short* __restrict__ WRfrag,
                                                 float* __restrict__ srel) {
    int tid  = threadIdx.x;
    int wv   = tid >> 6;
    int lane = tid & 63;
    int row0 = blockIdx.x * 64 + wv * 16;       // global row base of this wave
    int r    = lane & 15;                        // A row within tile
    int sg   = lane >> 4;                        // k sub-group

    // preload all 16 B-frags (16 B each, contiguous per kt across lanes)
    bf16x8 bf[16];
#pragma unroll
    for (int kt = 0; kt < 16; ++kt)
        bf[kt] = *(const bf16x8*)&WRfrag[((size_t)kt * 64 + lane) * 8];

    const float* ap = rel + (size_t)(row0 + r) * 512 + sg * 8;

    f32x4 acc = {0.f, 0.f, 0.f, 0.f};
#pragma unroll 4
    for (int kt = 0; kt < 16; ++kt) {
        float4 x0 = *(const float4*)(ap + kt * 32);
        float4 x1 = *(const float4*)(ap + kt * 32 + 4);
        bf16x8 a;
        a[0] = (short)f2bf(x0.x); a[1] = (short)f2bf(x0.y);
        a[2] = (short)f2bf(x0.z); a[3] = (short)f2bf(x0.w);
        a[4] = (short)f2bf(x1.x); a[5] = (short)f2bf(x1.y);
        a[6] = (short)f2bf(x1.z); a[7] = (short)f2bf(x1.w);
        acc = __builtin_amdgcn_mfma_f32_16x16x32_bf16(a, bf[kt], acc, 0, 0, 0);
    }

    // C: col n = lane&15 (= head, n<8), row j = row0 + sg*4 + reg
    int n = lane & 15;
    if (n < 8) {
        int bi = row0 >> 8;                      // 64-row blocks never straddle bi
        int jb = (row0 & 255) + sg * 4;
        float* sp = srel + (size_t)bi * 2048 + n * 256 + jb;
        sp[0] = acc[0]; sp[1] = acc[1]; sp[2] = acc[2]; sp[3] = acc[3];
    }
}

// ---------------- Kernel E: softmax + PV + residual. Block = one (b,i).
__global__ __launch_bounds__(256) void k_attn(const int*   __restrict__ mask,   // [bi][j]
                                              const float* __restrict__ adj,    // [b][h][i][j]
                                              const float* __restrict__ inp,    // [bi][D]
                                              const float* __restrict__ value,  // [b][h][j][dv]
                                              const float* __restrict__ srel,   // [bi][h][j]
                                              const float* __restrict__ s_src,  // [b][h][j]
                                              const float* __restrict__ s_tgt,  // [b][h][i]
                                              float* __restrict__ out) {        // [bi][D]
    __shared__ float attn_s[2048];     // [h][j]
    int bi  = blockIdx.x;
    int b   = bi >> 8;
    int i   = bi & 255;
    int tid = threadIdx.x;

    {
        int h  = tid >> 5;
        int ln = tid & 31;
        float stgt = s_tgt[(size_t)(b * 8 + h) * 256 + i];
        const float* ssrc   = s_src + (size_t)(b * 8 + h) * 256;
        const float* srl    = srel + (size_t)bi * 2048 + h * 256;
        const float* adjrow = adj + ((size_t)(b * 8 + h) * 256 + i) * 256;
        const int*   mrow   = mask + (size_t)bi * 256;

        float sc[8], av[8];
        int mb = 0;
        float rowmax = -3.0e38f;
#pragma unroll
        for (int t = 0; t < 8; ++t) {
            int j = ln + 32 * t;
            float a = adjrow[j];
            av[t] = a;
            int m = mrow[j];
            float s = ssrc[j] + stgt + srl[j];
            s = (s >= 0.f) ? s : 0.2f * s;     // leaky relu
            if (m != 0) { s = -NEGINF; mb |= (1 << t); }
            if (a == 0.f) s = -NEGINF;
            sc[t] = s;
            rowmax = fmaxf(rowmax, s);
        }
#pragma unroll
        for (int off = 16; off >= 1; off >>= 1)
            rowmax = fmaxf(rowmax, __shfl_xor(rowmax, off));

        float rowsum = 0.f;
#pragma unroll
        for (int t = 0; t < 8; ++t) {
            sc[t] = expf(sc[t] - rowmax);
            rowsum += sc[t];
        }
#pragma unroll
        for (int off = 16; off >= 1; off >>= 1)
            rowsum += __shfl_xor(rowsum, off);
        float rinv = 1.0f / rowsum;

        float sumabs = 0.f;
#pragma unroll
        for (int t = 0; t < 8; ++t) {
            float p = sc[t] * rinv;
            float invv = (av[t] == 0.f) ? 1e-12f : (1.0f / av[t]);
            p *= invv;
            sc[t] = p;
            sumabs += fabsf(p);
        }
#pragma unroll
        for (int off = 16; off >= 1; off >>= 1)
            sumabs += __shfl_xor(sumabs, off);

        float rdn = 1.0f / fmaxf(sumabs, 1e-12f);
#pragma unroll
        for (int t = 0; t < 8; ++t) {
            float p = sc[t] * rdn;
            if (mb & (1 << t)) p = 0.f;
            if (av[t] == 0.f) p = 0.f;
            attn_s[h * 256 + ln + 32 * t] = p;
        }
    }
    __syncthreads();

    {
        int h  = tid >> 5;
        int d0 = (tid & 31) * 2;
        const float* vbase = value + ((size_t)(b * 8 + h) * 256) * 64 + d0;
        const float* arow  = attn_s + h * 256;
        float ax = 0.f, ay = 0.f;
#pragma unroll 8
        for (int j = 0; j < 256; ++j) {
            float a = arow[j];
            float2 v2 = *(const float2*)(vbase + (size_t)j * 64);
            ax = fmaf(a, v2.x, ax);
            ay = fmaf(a, v2.y, ay);
        }
        size_t o = (size_t)bi * 512 + h * 64 + d0;
        out[o]     = inp[o] + ax;
        out[o + 1] = inp[o + 1] + ay;
    }
}

extern "C" void kernel_launch(void* const* d_in, const int* in_sizes, int n_in,
                              void* d_out, int out_size, void* d_ws, size_t ws_size,
                              hipStream_t stream) {
    const float* inp      = (const float*)d_in[0];
    const float* rel      = (const float*)d_in[1];
    const int*   mask     = (const int*)  d_in[2];
    const float* adj      = (const float*)d_in[3];
    const float* W_value  = (const float*)d_in[4];
    const float* W_rel    = (const float*)d_in[5];
    const float* w_src    = (const float*)d_in[6];
    const float* w_tgt    = (const float*)d_in[7];
    const float* w_rel    = (const float*)d_in[8];
    float* out = (float*)d_out;

    float* ws               = (float*)d_ws;
    float* value            = ws + WS_VALUE;
    float* WR               = ws + WS_WR;
    unsigned short* WRfrag  = (unsigned short*)(ws + WS_WRFRG);
    float* s_src            = ws + WS_SSRC;
    float* s_tgt            = ws + WS_STGT;
    float* srel             = ws + WS_SREL;

    k_wr<<<16, 256, 0, stream>>>(W_rel, w_rel, WR);
    k_frag<<<4, 256, 0, stream>>>(WR, WRfrag);
    k_value<<<256, 256, 0, stream>>>(inp, W_value, w_src, w_tgt,
                                     value, s_src, s_tgt);
    k_srel<<<2048, 256, 0, stream>>>(rel, WRfrag, srel);
    k_attn<<<B_ * L_, 256, 0, stream>>>(mask, adj, inp, value, srel,
                                        s_src, s_tgt, out);
}

// Round 8
// 115.335 us; speedup vs baseline: 1.3696x; 1.3696x over previous
//
#include <hip/hip_runtime.h>

#define B_ 2
#define L_ 256
#define D_ 512
#define H_ 8
#define DV_ 64
#define NEGINF 1e12f

// ws layout (float offsets):
#define WS_VALUE 0          // [B*H][L][DV]  = 262144
#define WS_WR    262144     // [512][8]      = 4096
#define WS_SSRC  266240     // [B*H][L]      = 4096
#define WS_STGT  270336     // [B*H][L]      = 4096

// ---------------- Kernel A: WR[k][h] = sum_d W_relation[k][h*64+d] * w_rel[h][d]
__global__ __launch_bounds__(256) void k_wr(const float* __restrict__ Wrel,
                                            const float* __restrict__ wrel,
                                            float* __restrict__ WR) {
    int flat = blockIdx.x * 256 + threadIdx.x;   // 4096 = 512*8
    int k = flat >> 3, h = flat & 7;
    const float* a = Wrel + k * 512 + h * 64;
    const float* b = wrel + h * 64;
    float s = 0.f;
#pragma unroll
    for (int d = 0; d < 64; d += 4) {
        float4 x = *(const float4*)(a + d);
        float4 y = *(const float4*)(b + d);
        s += x.x * y.x + x.y * y.y + x.z * y.z + x.w * y.w;
    }
    WR[k * 8 + h] = s;
}

// ---------------- Kernel B: value = inp @ W_value, + fused s_src/s_tgt epilogue
__global__ __launch_bounds__(256) void k_value(const float* __restrict__ inp,
                                               const float* __restrict__ Wv,
                                               const float* __restrict__ wsrc,
                                               const float* __restrict__ wtgt,
                                               float* __restrict__ value,
                                               float* __restrict__ s_src,
                                               float* __restrict__ s_tgt) {
    int blk = blockIdx.x;          // 256 blocks = 128 row-tiles x 2 col-halves
    int ct  = blk & 1;
    int rt  = blk >> 1;
    int n   = ct * 256 + threadIdx.x;   // output col 0..511
    int r0  = rt * 4;
    const float* i0 = inp + (size_t)(r0 + 0) * 512;
    const float* i1 = inp + (size_t)(r0 + 1) * 512;
    const float* i2 = inp + (size_t)(r0 + 2) * 512;
    const float* i3 = inp + (size_t)(r0 + 3) * 512;
    float a0 = 0.f, a1 = 0.f, a2 = 0.f, a3 = 0.f;
#pragma unroll 16
    for (int k = 0; k < 512; ++k) {
        float w = Wv[(size_t)k * 512 + n];
        a0 = fmaf(i0[k], w, a0);
        a1 = fmaf(i1[k], w, a1);
        a2 = fmaf(i2[k], w, a2);
        a3 = fmaf(i3[k], w, a3);
    }
    int h = n >> 6, dv = n & 63;
    float acc[4] = {a0, a1, a2, a3};
    float wsv = wsrc[h * 64 + dv];
    float wtv = wtgt[h * 64 + dv];
#pragma unroll
    for (int r = 0; r < 4; ++r) {
        int row = r0 + r;
        int b = row >> 8, l = row & 255;
        value[(((size_t)(b * 8 + h)) * 256 + l) * 64 + dv] = acc[r];
        float ss = acc[r] * wsv;
        float st = acc[r] * wtv;
#pragma unroll
        for (int off = 32; off >= 1; off >>= 1) {
            ss += __shfl_xor(ss, off);
            st += __shfl_xor(st, off);
        }
        if (dv == 0) {
            s_src[(size_t)(b * 8 + h) * 256 + l] = ss;
            s_tgt[(size_t)(b * 8 + h) * 256 + l] = st;
        }
    }
}

// ---------------- Kernel D: fused s_rel + softmax + out, MASK-COMPACTED.
// Block = one (b,i). Rows j with mask[b,i,j]!=0 are skipped entirely (their
// scores are -INF and attn 0 regardless of s_rel). Compacted row list in LDS;
// staging + compute iterate only over ~50% of rows.
__global__ __launch_bounds__(256) void k_main(const float* __restrict__ rel,    // [bi][j][k]
                                              const int*   __restrict__ mask,   // [bi][j]
                                              const float* __restrict__ adj,    // [b][h][i][j]
                                              const float* __restrict__ inp,    // [bi][D]
                                              const float* __restrict__ value,  // [b][h][j][dv]
                                              const float* __restrict__ WR,     // [k][h]
                                              const float* __restrict__ s_src,  // [b][h][j]
                                              const float* __restrict__ s_tgt,  // [b][h][i]
                                              float* __restrict__ out) {        // [bi][D]
    __shared__ float tile[256 * 64];   // 64 KB; reused for srel/attn after phase 1
    __shared__ int   list_s[256];
    __shared__ int   wavecnt[4];
    __shared__ int   count_s;
    int bi   = blockIdx.x;
    int b    = bi >> 8;
    int i    = bi & 255;
    int tid  = threadIdx.x;
    int lane = tid & 63;
    int wv   = tid >> 6;

    // ---- Phase 0: compact unmasked rows (row j = tid)
    const int* mrow = mask + (size_t)bi * 256;
    int mymask = mrow[tid];
    unsigned long long vote = __ballot(mymask == 0);
    int prefix = __popcll(vote & ((1ull << lane) - 1ull));
    if (lane == 0) wavecnt[wv] = __popcll(vote);
    __syncthreads();
    int base = 0;
    for (int wq = 0; wq < wv; ++wq) base += wavecnt[wq];
    if (mymask == 0) list_s[base + prefix] = tid;
    if (tid == 0) count_s = wavecnt[0] + wavecnt[1] + wavecnt[2] + wavecnt[3];
    __syncthreads();
    int count = count_s;               // block-uniform

    // ---- Phase 1: acc[h] = rel[bi, list[t], :] . WR[:, h], k-tiled through LDS
    float acc[8];
#pragma unroll
    for (int h = 0; h < 8; ++h) acc[h] = 0.f;

    const float* relbase = rel + (size_t)bi * 256 * 512;
    int nf    = count * 16;            // float4 slots per k-tile
    int niter = (nf + 255) >> 8;

    for (int kt = 0; kt < 8; ++kt) {
        int k0 = kt * 64;
        // stage: count rows x 64 floats, 256B-dense row slices, XOR-swizzled
        for (int ii = 0; ii < niter; ++ii) {
            int f = ii * 256 + tid;
            if (f < nf) {
                int r = f >> 4;            // compact row index
                int c = f & 15;            // chunk
                int row = list_s[r];
                float4 v = *(const float4*)(relbase + (size_t)row * 512 + k0 + c * 4);
                int wd = r * 64 + ((c ^ (r & 15)) << 2);
                *(float4*)&tile[wd] = v;
            }
        }
        __syncthreads();

        if (tid < count) {
            const float* wrt = WR + k0 * 8;    // wave-uniform -> s_load
#pragma unroll
            for (int c = 0; c < 16; ++c) {
                float4 x = *(const float4*)&tile[tid * 64 + ((c ^ (tid & 15)) << 2)];
#pragma unroll
                for (int h = 0; h < 8; ++h) {
                    acc[h] = fmaf(x.x, wrt[(c * 4 + 0) * 8 + h],
                             fmaf(x.y, wrt[(c * 4 + 1) * 8 + h],
                             fmaf(x.z, wrt[(c * 4 + 2) * 8 + h],
                             fmaf(x.w, wrt[(c * 4 + 3) * 8 + h], acc[h]))));
                }
            }
        }
        __syncthreads();
    }

    // publish srel (scatter by real row); masked rows keep garbage -> phase 2
    // overwrites them with -INF before use (finite leftovers, never NaN)
    float* srel_s = tile;              // [h][j]
    float* attn_s = tile + 2048;       // [h][j]
    if (tid < count) {
        int row = list_s[tid];
#pragma unroll
        for (int h = 0; h < 8; ++h) srel_s[h * 256 + row] = acc[h];
    }
    __syncthreads();

    // ---- Phase 2: per-h row softmax over j; 32 lanes per h, 8 j per lane
    {
        int h  = tid >> 5;
        int ln = tid & 31;
        float stgt = s_tgt[(size_t)(b * 8 + h) * 256 + i];
        const float* ssrc   = s_src + (size_t)(b * 8 + h) * 256;
        const float* adjrow = adj + ((size_t)(b * 8 + h) * 256 + i) * 256;

        float sc[8], av[8];
        int mb = 0;
        float rowmax = -3.0e38f;
#pragma unroll
        for (int t = 0; t < 8; ++t) {
            int j = ln + 32 * t;
            float a = adjrow[j];
            av[t] = a;
            int m = mrow[j];
            float s = ssrc[j] + stgt + srel_s[h * 256 + j];
            s = (s >= 0.f) ? s : 0.2f * s;     // leaky relu
            if (m != 0) { s = -NEGINF; mb |= (1 << t); }
            if (a == 0.f) s = -NEGINF;
            sc[t] = s;
            rowmax = fmaxf(rowmax, s);
        }
#pragma unroll
        for (int off = 16; off >= 1; off >>= 1)
            rowmax = fmaxf(rowmax, __shfl_xor(rowmax, off));

        float rowsum = 0.f;
#pragma unroll
        for (int t = 0; t < 8; ++t) {
            sc[t] = expf(sc[t] - rowmax);
            rowsum += sc[t];
        }
#pragma unroll
        for (int off = 16; off >= 1; off >>= 1)
            rowsum += __shfl_xor(rowsum, off);
        float rinv = 1.0f / rowsum;

        float sumabs = 0.f;
#pragma unroll
        for (int t = 0; t < 8; ++t) {
            float p = sc[t] * rinv;
            float invv = (av[t] == 0.f) ? 1e-12f : (1.0f / av[t]);
            p *= invv;
            sc[t] = p;
            sumabs += fabsf(p);
        }
#pragma unroll
        for (int off = 16; off >= 1; off >>= 1)
            sumabs += __shfl_xor(sumabs, off);

        float rdn = 1.0f / fmaxf(sumabs, 1e-12f);
#pragma unroll
        for (int t = 0; t < 8; ++t) {
            float p = sc[t] * rdn;
            if (mb & (1 << t)) p = 0.f;
            if (av[t] == 0.f) p = 0.f;
            attn_s[h * 256 + ln + 32 * t] = p;
        }
    }
    __syncthreads();

    // ---- Phase 3: out[bi][h*64+d] = inp + sum_j attn[h][j] * value[b][h][j][d]
    {
        int h  = tid >> 5;
        int d0 = (tid & 31) * 2;
        const float* vbase = value + ((size_t)(b * 8 + h) * 256) * 64 + d0;
        const float* arow  = attn_s + h * 256;
        float ax = 0.f, ay = 0.f;
#pragma unroll 8
        for (int j = 0; j < 256; ++j) {
            float a = arow[j];
            float2 v2 = *(const float2*)(vbase + (size_t)j * 64);
            ax = fmaf(a, v2.x, ax);
            ay = fmaf(a, v2.y, ay);
        }
        size_t o = (size_t)bi * 512 + h * 64 + d0;
        out[o]     = inp[o] + ax;
        out[o + 1] = inp[o + 1] + ay;
    }
}

extern "C" void kernel_launch(void* const* d_in, const int* in_sizes, int n_in,
                              void* d_out, int out_size, void* d_ws, size_t ws_size,
                              hipStream_t stream) {
    const float* inp      = (const float*)d_in[0];
    const float* rel      = (const float*)d_in[1];
    const int*   mask     = (const int*)  d_in[2];
    const float* adj      = (const float*)d_in[3];
    const float* W_value  = (const float*)d_in[4];
    const float* W_rel    = (const float*)d_in[5];
    const float* w_src    = (const float*)d_in[6];
    const float* w_tgt    = (const float*)d_in[7];
    const float* w_rel    = (const float*)d_in[8];
    float* out = (float*)d_out;

    float* ws    = (float*)d_ws;
    float* value = ws + WS_VALUE;
    float* WR    = ws + WS_WR;
    float* s_src = ws + WS_SSRC;
    float* s_tgt = ws + WS_STGT;

    k_wr<<<16, 256, 0, stream>>>(W_rel, w_rel, WR);
    k_value<<<256, 256, 0, stream>>>(inp, W_value, w_src, w_tgt,
                                     value, s_src, s_tgt);
    k_main<<<B_ * L_, 256, 0, stream>>>(rel, mask, adj, inp, value, WR,
                                        s_src, s_tgt, out);
}